// Round 1
// baseline (1164.845 us; speedup 1.0000x reference)
//
#include <hip/hip_runtime.h>

typedef __attribute__((ext_vector_type(8))) short bf16x8;
typedef __attribute__((ext_vector_type(4))) float f32x4;
typedef unsigned short ushort_t;
typedef unsigned int uint32;

#define DEV __device__ __forceinline__

// round-to-nearest-even f32 -> bf16 (bits)
DEV ushort_t f2bf(float f) {
    uint32 u = __float_as_uint(f);
    uint32 r = (u + 0x7FFFu + ((u >> 16) & 1u)) >> 16;
    return (ushort_t)r;
}

#define MFMA16(a, b, c) __builtin_amdgcn_mfma_f32_16x16x32_bf16((a), (b), (c), 0, 0, 0)

// async global->LDS, 16B per lane. LDS dest is wave-uniform base (readfirstlane)
// + lane*16; we pass per-lane pointers that are exactly base + lane*16.
DEV void gload_lds16(const void* g, void* l) {
    __builtin_amdgcn_global_load_lds((const __attribute__((address_space(1))) void*)g,
                                     (__attribute__((address_space(3))) void*)l,
                                     16, 0, 0);
}

// ---------------------------------------------------------------------------
// init: copy f32 x -> d_out (running x buffer) and bf16 xb
// ---------------------------------------------------------------------------
__global__ __launch_bounds__(256) void init_x(const float* __restrict__ xin,
                                              float* __restrict__ x,
                                              ushort_t* __restrict__ xb, int n4) {
    int i = blockIdx.x * 256 + threadIdx.x;
    if (i >= n4) return;
    float4 v = ((const float4*)xin)[i];
    ((float4*)x)[i] = v;
    ushort4 h;
    h.x = f2bf(v.x); h.y = f2bf(v.y); h.z = f2bf(v.z); h.w = f2bf(v.w);
    ((ushort4*)xb)[i] = h;
}

// ---------------------------------------------------------------------------
// transpose + convert: src (K x N f32, row-major) -> dst (N x K bf16)
// ---------------------------------------------------------------------------
__global__ __launch_bounds__(256) void transpose_convert(const float* __restrict__ src,
                                                         ushort_t* __restrict__ dst,
                                                         int K, int N) {
    __shared__ float tile[32][33];
    int tx = threadIdx.x, ty = threadIdx.y;  // (32,8)
    int nt = blockIdx.x * 32, kt = blockIdx.y * 32;
#pragma unroll
    for (int j = 0; j < 4; ++j)
        tile[ty + j * 8][tx] = src[(size_t)(kt + ty + j * 8) * N + nt + tx];
    __syncthreads();
#pragma unroll
    for (int j = 0; j < 4; ++j)
        dst[(size_t)(nt + ty + j * 8) * K + kt + tx] = f2bf(tile[tx][ty + j * 8]);
}

// ---------------------------------------------------------------------------
// GEMM: C[M,N] = A[M,K] @ BT[N,K]^T + bias (bf16 in, f32 acc)
// 128x128 tile, BK=32, 4 waves (2x2), each wave 64x64 = 4x4 16x16 frags
// ---------------------------------------------------------------------------
template <int OUT_BF16, int RELU>
__global__ __launch_bounds__(256) void gemm_bt(const ushort_t* __restrict__ A,
                                               const ushort_t* __restrict__ BT,
                                               const float* __restrict__ bias,
                                               void* __restrict__ Cout,
                                               int M, int N, int K) {
    __shared__ ushort_t a_lds[128 * 32];
    __shared__ ushort_t b_lds[128 * 32];
    const int tid = threadIdx.x;
    const int w = tid >> 6, lane = tid & 63;
    const int wm = w >> 1, wn = w & 1;
    const int lr = lane & 15, lh = lane >> 4;
    const int row0 = blockIdx.y * 128, col0 = blockIdx.x * 128;

    f32x4 acc[4][4] = {};

    const int e0 = tid * 8;          // LDS elem offset, chunk 0 (16B per lane)
    const int r0 = e0 >> 5, c0 = e0 & 31;
    const int e1 = e0 + 2048;        // chunk 1
    const int r1 = r0 + 64;

    const ushort_t* Ab = A + (size_t)row0 * K;
    const ushort_t* Bb = BT + (size_t)col0 * K;

    for (int k0 = 0; k0 < K; k0 += 32) {
        __syncthreads();
        gload_lds16(Ab + (size_t)r0 * K + k0 + c0, &a_lds[e0]);
        gload_lds16(Ab + (size_t)r1 * K + k0 + c0, &a_lds[e1]);
        gload_lds16(Bb + (size_t)r0 * K + k0 + c0, &b_lds[e0]);
        gload_lds16(Bb + (size_t)r1 * K + k0 + c0, &b_lds[e1]);
        __syncthreads();  // drains vmcnt (global_load_lds) + barrier

        bf16x8 af[4], bfr[4];
#pragma unroll
        for (int mi = 0; mi < 4; ++mi)
            af[mi] = *(const bf16x8*)&a_lds[(wm * 64 + mi * 16 + lr) * 32 + lh * 8];
#pragma unroll
        for (int ni = 0; ni < 4; ++ni)
            bfr[ni] = *(const bf16x8*)&b_lds[(wn * 64 + ni * 16 + lr) * 32 + lh * 8];
#pragma unroll
        for (int mi = 0; mi < 4; ++mi)
#pragma unroll
            for (int ni = 0; ni < 4; ++ni)
                acc[mi][ni] = MFMA16(af[mi], bfr[ni], acc[mi][ni]);
    }

#pragma unroll
    for (int mi = 0; mi < 4; ++mi) {
#pragma unroll
        for (int ni = 0; ni < 4; ++ni) {
            const int col = col0 + wn * 64 + ni * 16 + lr;
            const float bv = bias[col];
#pragma unroll
            for (int r = 0; r < 4; ++r) {
                const int row = row0 + wm * 64 + mi * 16 + lh * 4 + r;
                float val = acc[mi][ni][r] + bv;
                if (RELU) val = fmaxf(val, 0.f);
                if (OUT_BF16)
                    ((ushort_t*)Cout)[(size_t)row * N + col] = f2bf(val);
                else
                    ((float*)Cout)[(size_t)row * N + col] = val;
            }
        }
    }
}

// ---------------------------------------------------------------------------
// fused causal flash attention: one block per (b,h,64-row q tile), 4 waves,
// wave = 16 q rows. key tiles of 32. q/k/v/o: (B*S, D) bf16, head offset h*64.
// ---------------------------------------------------------------------------
__global__ __launch_bounds__(256) void attn_kernel(const ushort_t* __restrict__ q,
                                                   const ushort_t* __restrict__ k,
                                                   const ushort_t* __restrict__ v,
                                                   ushort_t* __restrict__ o) {
    __shared__ ushort_t vtile[32 * 64];
    __shared__ ushort_t p_lds[4][16 * 32];

    const int bh = blockIdx.y;
    const int b = bh >> 4, h = bh & 15;
    const int qt = blockIdx.x;
    const int tid = threadIdx.x, w = tid >> 6, lane = tid & 63;
    const int lr = lane & 15, lh = lane >> 4;
    const int qbase = qt * 64 + w * 16;
    const size_t headoff = (size_t)b * 1024 * 1024 + h * 64;

    bf16x8 qf[2];
#pragma unroll
    for (int ks = 0; ks < 2; ++ks)
        qf[ks] = *(const bf16x8*)&q[headoff + (size_t)(qbase + lr) * 1024 + ks * 32 + lh * 8];

    f32x4 oacc[4] = {};
    float m[4] = {-INFINITY, -INFINITY, -INFINITY, -INFINITY};
    float ls[4] = {0.f, 0.f, 0.f, 0.f};

    const int jmax = qt * 64 + 63;
    for (int j0 = 0; j0 <= jmax; j0 += 32) {
        __syncthreads();
        {  // stage V tile 32x64 cooperatively
            const int r = tid >> 3, c = (tid & 7) * 8;
            *(bf16x8*)&vtile[r * 64 + c] =
                *(const bf16x8*)&v[headoff + (size_t)(j0 + r) * 1024 + c];
        }
        __syncthreads();

        if (j0 <= qbase + 15) {  // tile not entirely above-diagonal for this wave
            f32x4 s0 = {}, s1 = {};
#pragma unroll
            for (int ks = 0; ks < 2; ++ks) {
                bf16x8 k0f = *(const bf16x8*)&k[headoff + (size_t)(j0 + lr) * 1024 + ks * 32 + lh * 8];
                s0 = MFMA16(qf[ks], k0f, s0);
                bf16x8 k1f = *(const bf16x8*)&k[headoff + (size_t)(j0 + 16 + lr) * 1024 + ks * 32 + lh * 8];
                s1 = MFMA16(qf[ks], k1f, s1);
            }
            const float scale = 0.125f;
#pragma unroll
            for (int r = 0; r < 4; ++r) {
                const int row = qbase + lh * 4 + r;
                s0[r] = ((j0 + lr) <= row) ? s0[r] * scale : -1e9f;
                s1[r] = ((j0 + 16 + lr) <= row) ? s1[r] * scale : -1e9f;
            }
            // online softmax (rows live in 16-lane groups)
#pragma unroll
            for (int r = 0; r < 4; ++r) {
                float pm = fmaxf(s0[r], s1[r]);
                pm = fmaxf(pm, __shfl_xor(pm, 1, 16));
                pm = fmaxf(pm, __shfl_xor(pm, 2, 16));
                pm = fmaxf(pm, __shfl_xor(pm, 4, 16));
                pm = fmaxf(pm, __shfl_xor(pm, 8, 16));
                const float mn = fmaxf(m[r], pm);
                const float corr = __expf(m[r] - mn);
                m[r] = mn;
                const float p0 = __expf(s0[r] - mn);
                const float p1 = __expf(s1[r] - mn);
                s0[r] = p0; s1[r] = p1;
                float ps = p0 + p1;
                ps += __shfl_xor(ps, 1, 16);
                ps += __shfl_xor(ps, 2, 16);
                ps += __shfl_xor(ps, 4, 16);
                ps += __shfl_xor(ps, 8, 16);
                ls[r] = ls[r] * corr + ps;
                oacc[0][r] *= corr; oacc[1][r] *= corr;
                oacc[2][r] *= corr; oacc[3][r] *= corr;
            }
            // P -> LDS (wave-private; LDS is in-order per wave, no barrier needed)
#pragma unroll
            for (int r = 0; r < 4; ++r) {
                p_lds[w][(lh * 4 + r) * 32 + lr] = f2bf(s0[r]);
                p_lds[w][(lh * 4 + r) * 32 + 16 + lr] = f2bf(s1[r]);
            }
            bf16x8 pa = *(const bf16x8*)&p_lds[w][lr * 32 + lh * 8];
#pragma unroll
            for (int dt = 0; dt < 4; ++dt) {
                bf16x8 vf;
#pragma unroll
                for (int e = 0; e < 8; ++e)
                    vf[e] = (short)vtile[(lh * 8 + e) * 64 + dt * 16 + lr];
                oacc[dt] = MFMA16(pa, vf, oacc[dt]);
            }
        }
    }

    float inv[4];
#pragma unroll
    for (int r = 0; r < 4; ++r) inv[r] = 1.f / ls[r];
#pragma unroll
    for (int dt = 0; dt < 4; ++dt)
#pragma unroll
        for (int r = 0; r < 4; ++r) {
            const int row = qbase + lh * 4 + r;
            o[headoff + (size_t)row * 1024 + dt * 16 + lr] = f2bf(oacc[dt][r] * inv[r]);
        }
}

// ---------------------------------------------------------------------------
// fused residual + LayerNorm: x = LN(t + x); writes f32 x and bf16 xb
// one block per row (D=1024), 256 threads x 4 elems
// ---------------------------------------------------------------------------
__global__ __launch_bounds__(256) void add_ln(const float* __restrict__ t,
                                              float* __restrict__ x,
                                              const float* __restrict__ g,
                                              const float* __restrict__ bb,
                                              ushort_t* __restrict__ xb) {
    const int row = blockIdx.x, tid = threadIdx.x;
    const int lane = tid & 63, w = tid >> 6;
    const size_t base = (size_t)row * 1024;
    float4 tv = ((const float4*)(t + base))[tid];
    float4 xv = ((const float4*)(x + base))[tid];
    float v0 = tv.x + xv.x, v1 = tv.y + xv.y, v2 = tv.z + xv.z, v3 = tv.w + xv.w;
    float s = v0 + v1 + v2 + v3;
    float sq = v0 * v0 + v1 * v1 + v2 * v2 + v3 * v3;
#pragma unroll
    for (int off = 32; off >= 1; off >>= 1) {
        s += __shfl_xor(s, off);
        sq += __shfl_xor(sq, off);
    }
    __shared__ float red[8];
    if (lane == 0) { red[w] = s; red[4 + w] = sq; }
    __syncthreads();
    s = red[0] + red[1] + red[2] + red[3];
    sq = red[4] + red[5] + red[6] + red[7];
    const float mu = s * (1.f / 1024.f);
    const float var = sq * (1.f / 1024.f) - mu * mu;
    const float rs = rsqrtf(var + 1e-6f);
    float4 gv = ((const float4*)g)[tid];
    float4 bv = ((const float4*)bb)[tid];
    float y0 = (v0 - mu) * rs * gv.x + bv.x;
    float y1 = (v1 - mu) * rs * gv.y + bv.y;
    float y2 = (v2 - mu) * rs * gv.z + bv.z;
    float y3 = (v3 - mu) * rs * gv.w + bv.w;
    float4 yo; yo.x = y0; yo.y = y1; yo.z = y2; yo.w = y3;
    ((float4*)(x + base))[tid] = yo;
    ushort4 h;
    h.x = f2bf(y0); h.y = f2bf(y1); h.z = f2bf(y2); h.w = f2bf(y3);
    ((ushort4*)(xb + base))[tid] = h;
}

// ---------------------------------------------------------------------------
extern "C" void kernel_launch(void* const* d_in, const int* in_sizes, int n_in,
                              void* d_out, int out_size, void* d_ws, size_t ws_size,
                              hipStream_t stream) {
    (void)in_sizes; (void)n_in; (void)out_size; (void)ws_size;
    const int B = 8, S = 1024, D = 1024, DFF = 4096, L = 2;
    const int M = B * S;  // 8192

    const float* x_in = (const float*)d_in[0];
    const float* Wq = (const float*)d_in[2];
    const float* bq = (const float*)d_in[3];
    const float* Wk = (const float*)d_in[4];
    const float* bk = (const float*)d_in[5];
    const float* Wv = (const float*)d_in[6];
    const float* bv = (const float*)d_in[7];
    const float* Wo = (const float*)d_in[8];
    const float* bo = (const float*)d_in[9];
    const float* W1 = (const float*)d_in[10];
    const float* b1 = (const float*)d_in[11];
    const float* W2 = (const float*)d_in[12];
    const float* b2 = (const float*)d_in[13];
    const float* ln1g = (const float*)d_in[14];
    const float* ln1b = (const float*)d_in[15];
    const float* ln2g = (const float*)d_in[16];
    const float* ln2b = (const float*)d_in[17];

    float* x = (float*)d_out;  // running f32 activation buffer
    char* ws = (char*)d_ws;
    const size_t MB = 1024 * 1024;
    ushort_t* wqT = (ushort_t*)(ws + 0 * MB);    // 4MB (2 layers)
    ushort_t* wkT = (ushort_t*)(ws + 4 * MB);
    ushort_t* wvT = (ushort_t*)(ws + 8 * MB);
    ushort_t* woT = (ushort_t*)(ws + 12 * MB);
    ushort_t* w1T = (ushort_t*)(ws + 16 * MB);   // 16MB
    ushort_t* w2T = (ushort_t*)(ws + 32 * MB);   // 16MB
    ushort_t* xb  = (ushort_t*)(ws + 48 * MB);   // 16MB
    ushort_t* qb  = (ushort_t*)(ws + 64 * MB);   // 16MB
    ushort_t* kb  = (ushort_t*)(ws + 80 * MB);   // 16MB
    ushort_t* vb  = (ushort_t*)(ws + 96 * MB);   // 16MB
    ushort_t* ob  = (ushort_t*)(ws + 112 * MB);  // 16MB
    ushort_t* hb  = (ushort_t*)(ws + 64 * MB);   // 64MB, reuses q/k/v/o region
    float* t      = (float*)(ws + 128 * MB);     // 32MB f32

    init_x<<<M * D / 4 / 256, 256, 0, stream>>>(x_in, x, xb, M * D / 4);

    dim3 tb(32, 8);
    for (int l = 0; l < L; ++l) {
        const size_t wOff = (size_t)l * D * D;
        transpose_convert<<<dim3(D / 32, D / 32), tb, 0, stream>>>(Wq + wOff, wqT + wOff, D, D);
        transpose_convert<<<dim3(D / 32, D / 32), tb, 0, stream>>>(Wk + wOff, wkT + wOff, D, D);
        transpose_convert<<<dim3(D / 32, D / 32), tb, 0, stream>>>(Wv + wOff, wvT + wOff, D, D);
        transpose_convert<<<dim3(D / 32, D / 32), tb, 0, stream>>>(Wo + wOff, woT + wOff, D, D);
        transpose_convert<<<dim3(DFF / 32, D / 32), tb, 0, stream>>>(W1 + (size_t)l * D * DFF, w1T + (size_t)l * D * DFF, D, DFF);
        transpose_convert<<<dim3(D / 32, DFF / 32), tb, 0, stream>>>(W2 + (size_t)l * DFF * D, w2T + (size_t)l * DFF * D, DFF, D);
    }

    const dim3 gP(D / 128, M / 128);      // (8, 64) projection GEMMs
    const dim3 gF1(DFF / 128, M / 128);   // (32, 64)
    const dim3 gF2(D / 128, M / 128);

    for (int l = 0; l < L; ++l) {
        const size_t wOff = (size_t)l * D * D;
        const size_t bOff = (size_t)l * D;
        gemm_bt<1, 0><<<gP, 256, 0, stream>>>(xb, wqT + wOff, bq + bOff, qb, M, D, D);
        gemm_bt<1, 0><<<gP, 256, 0, stream>>>(xb, wkT + wOff, bk + bOff, kb, M, D, D);
        gemm_bt<1, 0><<<gP, 256, 0, stream>>>(xb, wvT + wOff, bv + bOff, vb, M, D, D);
        attn_kernel<<<dim3(S / 64, B * 16), 256, 0, stream>>>(qb, kb, vb, ob);
        gemm_bt<0, 0><<<gP, 256, 0, stream>>>(ob, woT + wOff, bo + bOff, t, M, D, D);
        add_ln<<<M, 256, 0, stream>>>(t, x, ln1g + bOff, ln1b + bOff, xb);
        gemm_bt<1, 1><<<gF1, 256, 0, stream>>>(xb, w1T + (size_t)l * D * DFF, b1 + (size_t)l * DFF, hb, M, DFF, D);
        gemm_bt<0, 0><<<gF2, 256, 0, stream>>>(hb, w2T + (size_t)l * DFF * D, b2 + bOff, t, M, D, DFF);
        add_ln<<<M, 256, 0, stream>>>(t, x, ln2g + bOff, ln2b + bOff, xb);
    }
}